// Round 4
// baseline (506.038 us; speedup 1.0000x reference)
//
#include <hip/hip_runtime.h>
#include <stdint.h>

typedef __bf16 bf16x8 __attribute__((ext_vector_type(8)));
typedef float f32x4 __attribute__((ext_vector_type(4)));

__device__ __forceinline__ float bf2f(uint16_t u) {
  union { uint32_t i; float f; } v; v.i = ((uint32_t)u) << 16; return v.f;
}
__device__ __forceinline__ uint16_t f2bf(float f) {
  union { float f; uint32_t i; } v; v.f = f;
  uint32_t u = v.i;
  uint32_t r = (u + 0x7FFFu + ((u >> 16) & 1u)) >> 16;
  return (uint16_t)r;
}
// gelu(v) = v * sigmoid(1.5957691*v*(1+0.044715*v^2))  (tanh-form identity).
__device__ __forceinline__ float fast_gelu(float v) {
  float t2 = v * v;
  float pz = 1.0f + 0.044715f * t2;
  float w = -1.5957691216f * v * pz;
  float e = __expf(w);
  return v * __builtin_amdgcn_rcpf(1.0f + e);
}

#define GLL(gp, lp) __builtin_amdgcn_global_load_lds( \
    (const __attribute__((address_space(1))) void*)(gp), \
    (__attribute__((address_space(3))) void*)(lp), 16, 0, 0)

// ---------------------------------------------------------------------------
// Kernel 0: fc1/fc2 fp32 -> bf16 into workspace.
// ---------------------------------------------------------------------------
__global__ __launch_bounds__(256) void cvt_weights_kernel(
    const float* __restrict__ fc1, const float* __restrict__ fc2,
    uint16_t* __restrict__ fc1b, uint16_t* __restrict__ fc2b)
{
  int i = (blockIdx.x * 256 + threadIdx.x) * 4;
  if (i < 262144) {
    float4 a = *(const float4*)(fc1 + i);
    ushort4 o;
    o.x = f2bf(a.x); o.y = f2bf(a.y); o.z = f2bf(a.z); o.w = f2bf(a.w);
    *(ushort4*)(fc1b + i) = o;
  } else {
    int j = i - 262144;
    float4 a = *(const float4*)(fc2 + j);
    ushort4 o;
    o.x = f2bf(a.x); o.y = f2bf(a.y); o.z = f2bf(a.z); o.w = f2bf(a.w);
    *(ushort4*)(fc2b + j) = o;
  }
}

// ---------------------------------------------------------------------------
// Kernel 1: NeoCell + BatchNorm(eval). x NCHW fp32 -> y1 (100352 x 256) bf16
// NHWC. (Unchanged from round 3.)
// ---------------------------------------------------------------------------
__global__ __launch_bounds__(128) void neocell_bn_kernel(
    const float* __restrict__ x,
    const float* __restrict__ wa1, const float* __restrict__ wb1,
    const float* __restrict__ wa2, const float* __restrict__ wb2,
    const float* __restrict__ bnw, const float* __restrict__ bnb,
    const float* __restrict__ bnm, const float* __restrict__ bnv,
    uint16_t* __restrict__ y1)
{
  __shared__ uint16_t lx[128 * 226];
  const int t = threadIdx.x;
  const int strip = blockIdx.x;
  const int b = blockIdx.y;
  const int half = blockIdx.z;
  const int h0 = strip * 4;

  for (int i = 0; i < 56; ++i) {
    int l = t + i * 128;
    int c = l / 56;
    int r = l - c * 56;
    const float* g = x + (size_t)(b * 256 + half * 128 + c) * 3136
                       + h0 * 56 + r * 4;
    float4 v = *(const float4*)g;
    ushort4 o;
    o.x = f2bf(v.x); o.y = f2bf(v.y); o.z = f2bf(v.z); o.w = f2bf(v.w);
    *(ushort4*)(lx + c * 226 + r * 4) = o;
  }
  __syncthreads();

  const int a = t & 63;
  const int p = t >> 6;
  const int c0 = half * 128 + 2 * a;

  float sc[2], sh[2];
#pragma unroll
  for (int ch = 0; ch < 2; ++ch) {
    int cg = c0 + ch;
    sc[ch] = bnw[cg] * rsqrtf(bnv[cg] + 1e-5f);
    sh[ch] = bnb[cg] - bnm[cg] * sc[ch];
  }
  const size_t pgbase = (size_t)b * 3136 + (size_t)h0 * 56;

  if (half == 0) {
    float A[2][2][2], Bm[2][2][2];
#pragma unroll
    for (int ch = 0; ch < 2; ++ch)
#pragma unroll
      for (int i = 0; i < 2; ++i)
#pragma unroll
        for (int j = 0; j < 2; ++j) {
          A[ch][i][j]  = wa1[(2 * a + ch) * 4 + i * 2 + j];
          Bm[ch][i][j] = wb1[(2 * a + ch) * 4 + i * 2 + j];
        }
    for (int m = 0; m < 28; ++m) {
      float O[2][2][2];
#pragma unroll
      for (int ch = 0; ch < 2; ++ch) {
        const uint16_t* lc = lx + (2 * a + ch) * 226 + (2 * p) * 56 + m * 2;
        uint32_t w0 = *(const uint32_t*)lc;
        uint32_t w1 = *(const uint32_t*)(lc + 56);
        float X[2][2];
        X[0][0] = bf2f((uint16_t)w0); X[0][1] = bf2f((uint16_t)(w0 >> 16));
        X[1][0] = bf2f((uint16_t)w1); X[1][1] = bf2f((uint16_t)(w1 >> 16));
        float T[2][2];
#pragma unroll
        for (int pp = 0; pp < 2; ++pp)
#pragma unroll
          for (int j = 0; j < 2; ++j)
            T[pp][j] = A[ch][pp][0] * X[0][j] + A[ch][pp][1] * X[1][j];
#pragma unroll
        for (int pp = 0; pp < 2; ++pp)
#pragma unroll
          for (int q = 0; q < 2; ++q)
            O[ch][pp][q] = (T[pp][0] * Bm[ch][0][q] + T[pp][1] * Bm[ch][1][q])
                           * sc[ch] + sh[ch];
      }
#pragma unroll
      for (int pp = 0; pp < 2; ++pp)
#pragma unroll
        for (int q = 0; q < 2; ++q) {
          uint32_t pk = (uint32_t)f2bf(O[0][pp][q])
                      | ((uint32_t)f2bf(O[1][pp][q]) << 16);
          size_t pg = pgbase + (size_t)(2 * p + pp) * 56 + (m * 2 + q);
          *(uint32_t*)(y1 + pg * 256 + c0) = pk;
        }
    }
  } else {
    float A[2][4][4], Bm[2][4][4];
#pragma unroll
    for (int ch = 0; ch < 2; ++ch)
#pragma unroll
      for (int i = 0; i < 4; ++i)
#pragma unroll
        for (int j = 0; j < 4; ++j) {
          A[ch][i][j]  = wa2[(2 * a + ch) * 16 + i * 4 + j];
          Bm[ch][i][j] = wb2[(2 * a + ch) * 16 + i * 4 + j];
        }
    for (int mm = 0; mm < 7; ++mm) {
      int m = 2 * mm + p;
      float O[2][4][4];
#pragma unroll
      for (int ch = 0; ch < 2; ++ch) {
        float X[4][4];
#pragma unroll
        for (int i = 0; i < 4; ++i) {
          const uint16_t* lc = lx + (2 * a + ch) * 226 + i * 56 + m * 4;
          uint32_t w0 = *(const uint32_t*)lc;
          uint32_t w1 = *(const uint32_t*)(lc + 2);
          X[i][0] = bf2f((uint16_t)w0); X[i][1] = bf2f((uint16_t)(w0 >> 16));
          X[i][2] = bf2f((uint16_t)w1); X[i][3] = bf2f((uint16_t)(w1 >> 16));
        }
        float T[4][4];
#pragma unroll
        for (int pp = 0; pp < 4; ++pp)
#pragma unroll
          for (int j = 0; j < 4; ++j)
            T[pp][j] = A[ch][pp][0] * X[0][j] + A[ch][pp][1] * X[1][j]
                     + A[ch][pp][2] * X[2][j] + A[ch][pp][3] * X[3][j];
#pragma unroll
        for (int pp = 0; pp < 4; ++pp)
#pragma unroll
          for (int q = 0; q < 4; ++q)
            O[ch][pp][q] = (T[pp][0] * Bm[ch][0][q] + T[pp][1] * Bm[ch][1][q]
                          + T[pp][2] * Bm[ch][2][q] + T[pp][3] * Bm[ch][3][q])
                           * sc[ch] + sh[ch];
      }
#pragma unroll
      for (int pp = 0; pp < 4; ++pp)
#pragma unroll
        for (int q = 0; q < 4; ++q) {
          uint32_t pk = (uint32_t)f2bf(O[0][pp][q])
                      | ((uint32_t)f2bf(O[1][pp][q]) << 16);
          size_t pg = pgbase + (size_t)pp * 56 + (m * 4 + q);
          *(uint32_t*)(y1 + pg * 256 + c0) = pk;
        }
    }
  }
}

// ---------------------------------------------------------------------------
// Fused MLP: per block (128 pixels x 128 out-cols), loop hc-chunks of 128:
//   phase1: h_chunk = y1_tile @ fc1_chunk^T (K=256, m97 loop) -> GELU -> LDS
//   phase2: oacc += h_chunk @ fc2_chunk^T   (K=128, A read from LDS panels)
// h never touches HBM (kills 410 MB of traffic). Each co-half recomputes h
// (phase-1 FLOPs x2; compute is cheap, memory was the wall).
// hbuf panel layout [4][128][32] keeps phase-2 A-frag reads in the proven
// conflict-free pitch-32 pattern. Epilogue = round-3 EPI1 transpose + fp32
// residual, unchanged.
// ---------------------------------------------------------------------------
__global__ __launch_bounds__(256, 2) void fused_mlp_kernel(
    const uint16_t* __restrict__ y1,    // [100352][256] bf16
    const uint16_t* __restrict__ fc1b,  // [1024][256] bf16
    const uint16_t* __restrict__ fc2b,  // [256][1024] bf16
    const float* __restrict__ x,        // NCHW fp32 residual
    float* __restrict__ out)            // NCHW fp32
{
  __shared__ uint16_t lds[24576];       // 48 KB
  uint16_t* ldsA = lds;                 // [128][32] y1 panel
  uint16_t* ldsB = lds + 4096;          // [128][32] fc1/fc2 panel (shared)
  uint16_t* hbuf = lds + 8192;          // [4][128][32] gelu(h) chunk

  const int tid = threadIdx.x;
  const int lane = tid & 63;
  const int wid = tid >> 6;
  const int wm = wid & 1;
  const int wn = wid >> 1;
  const int fm = lane & 15;
  const int fq = lane >> 4;

  const int coh = blockIdx.x;                       // 0/1: out-col half
  const size_t pix0 = (size_t)blockIdx.y * 128;     // pixel-tile base

  f32x4 oacc[4][4];
#pragma unroll
  for (int i = 0; i < 4; ++i)
#pragma unroll
    for (int j = 0; j < 4; ++j) { f32x4 z = {0.f, 0.f, 0.f, 0.f}; oacc[i][j] = z; }

  const int q0 = tid, q1 = tid + 256;
  const int r0 = q0 >> 2, kk0 = q0 & 3;
  const int r1 = q1 >> 2, kk1 = q1 & 3;

  const uint16_t* a0 = y1 + (pix0 + r0) * 256 + kk0 * 8;
  const uint16_t* a1 = y1 + (pix0 + r1) * 256 + kk1 * 8;
  const uint16_t* f20 = fc2b + ((size_t)coh * 128 + r0) * 1024 + kk0 * 8;
  const uint16_t* f21 = fc2b + ((size_t)coh * 128 + r1) * 1024 + kk1 * 8;

  for (int c = 0; c < 8; ++c) {
    const int hc0 = c * 128;
    const uint16_t* b0 = fc1b + (size_t)(hc0 + r0) * 256 + kk0 * 8;
    const uint16_t* b1 = fc1b + (size_t)(hc0 + r1) * 256 + kk1 * 8;

    // ---- phase 1: h_chunk(128x128) = y1_tile @ fc1_chunk^T ----
    f32x4 hacc[4][4];
#pragma unroll
    for (int i = 0; i < 4; ++i)
#pragma unroll
      for (int j = 0; j < 4; ++j) { f32x4 z = {0.f, 0.f, 0.f, 0.f}; hacc[i][j] = z; }

    for (int k0 = 0; k0 < 256; k0 += 32) {
      __syncthreads();
      GLL(a0 + k0, ldsA + q0 * 8);
      GLL(a1 + k0, ldsA + q1 * 8);
      GLL(b0 + k0, ldsB + q0 * 8);
      GLL(b1 + k0, ldsB + q1 * 8);
      __syncthreads();

      bf16x8 af[4], bfr[4];
#pragma unroll
      for (int mt = 0; mt < 4; ++mt)
        af[mt] = *(const bf16x8*)(const void*)
                 (ldsA + (wm * 64 + mt * 16 + fm) * 32 + fq * 8);
#pragma unroll
      for (int nt = 0; nt < 4; ++nt)
        bfr[nt] = *(const bf16x8*)(const void*)
                  (ldsB + (wn * 64 + nt * 16 + fm) * 32 + fq * 8);
#pragma unroll
      for (int mt = 0; mt < 4; ++mt)
#pragma unroll
        for (int nt = 0; nt < 4; ++nt)
          hacc[mt][nt] = __builtin_amdgcn_mfma_f32_16x16x32_bf16(
              af[mt], bfr[nt], hacc[mt][nt], 0, 0, 0);
    }

    // ---- GELU -> hbuf (panel layout [hc>>5][pix][hc&31]) ----
    // C layout: col(hc)=fm within tile, row(pix)=fq*4+r. No barrier needed:
    // writes go to hbuf, staging regions untouched; phase-2's first barrier
    // orders all h-writes before any h-read.
#pragma unroll
    for (int mt = 0; mt < 4; ++mt) {
      int pixl = wm * 64 + mt * 16 + fq * 4;
#pragma unroll
      for (int nt = 0; nt < 4; ++nt) {
        int hcl = wn * 64 + nt * 16 + fm;
        uint16_t* hp = hbuf + ((hcl >> 5) << 12) + (hcl & 31);
#pragma unroll
        for (int r = 0; r < 4; ++r)
          hp[(pixl + r) * 32] = f2bf(fast_gelu(hacc[mt][nt][r]));
      }
    }

    // ---- phase 2: oacc += h_chunk @ fc2_chunk^T (K=128) ----
    for (int kp = 0; kp < 4; ++kp) {
      __syncthreads();   // drains h-writes; frees ldsB for fc2 panel
      GLL(f20 + hc0 + kp * 32, ldsB + q0 * 8);
      GLL(f21 + hc0 + kp * 32, ldsB + q1 * 8);
      __syncthreads();

      bf16x8 haf[4], cfr[4];
#pragma unroll
      for (int mt = 0; mt < 4; ++mt)
        haf[mt] = *(const bf16x8*)(const void*)
                  (hbuf + (kp << 12) + (wm * 64 + mt * 16 + fm) * 32 + fq * 8);
#pragma unroll
      for (int nt = 0; nt < 4; ++nt)
        cfr[nt] = *(const bf16x8*)(const void*)
                  (ldsB + (wn * 64 + nt * 16 + fm) * 32 + fq * 8);
#pragma unroll
      for (int mt = 0; mt < 4; ++mt)
#pragma unroll
        for (int nt = 0; nt < 4; ++nt)
          oacc[mt][nt] = __builtin_amdgcn_mfma_f32_16x16x32_bf16(
              haf[mt], cfr[nt], oacc[mt][nt], 0, 0, 0);
    }
  }

  // ---- epilogue: LDS transpose -> NCHW fp32 + fused residual ----
  __syncthreads();
#pragma unroll
  for (int mt = 0; mt < 4; ++mt) {
    int mbase = wm * 64 + mt * 16 + fq * 4;       // pixel within tile
#pragma unroll
    for (int nt = 0; nt < 4; ++nt) {
      int n = wn * 64 + nt * 16 + fm;             // out-col within half
#pragma unroll
      for (int r = 0; r < 4; ++r)
        lds[n * 130 + mbase + r] = f2bf(oacc[mt][nt][r]);
    }
  }
  __syncthreads();
  const int pl0 = tid & 31;
  const int cw = tid >> 5;
#pragma unroll
  for (int it = 0; it < 16; ++it) {
    int ch = cw + it * 8;                          // col within half
    int cgl = coh * 128 + ch;                      // global out channel
#pragma unroll
    for (int e = 0; e < 4; ++e) {
      int pl = pl0 + e * 32;                       // pixel within tile
      uint32_t pg = (uint32_t)pix0 + (uint32_t)pl;
      uint32_t bimg = pg / 3136u;
      uint32_t rem = pg - bimg * 3136u;
      size_t addr = ((size_t)bimg * 256 + cgl) * 3136 + rem;
      out[addr] = bf2f(lds[ch * 130 + pl]) + x[addr];
    }
  }
}

// ---------------------------------------------------------------------------
// Launch: cvt weights -> neocell -> fused MLP (single pass, no h in HBM).
// ---------------------------------------------------------------------------
extern "C" void kernel_launch(void* const* d_in, const int* in_sizes, int n_in,
                              void* d_out, int out_size, void* d_ws,
                              size_t ws_size, hipStream_t stream)
{
  const float* x   = (const float*)d_in[0];
  const float* wa1 = (const float*)d_in[1];
  const float* wb1 = (const float*)d_in[2];
  const float* wa2 = (const float*)d_in[3];
  const float* wb2 = (const float*)d_in[4];
  const float* bnw = (const float*)d_in[5];
  const float* bnb = (const float*)d_in[6];
  const float* bnm = (const float*)d_in[7];
  const float* bnv = (const float*)d_in[8];
  const float* fc1 = (const float*)d_in[9];
  const float* fc2 = (const float*)d_in[10];
  float* out = (float*)d_out;

  uint16_t* fc1b = (uint16_t*)d_ws;                 // 512 KB
  uint16_t* fc2b = fc1b + 262144;                   // 512 KB
  uint16_t* y1 = fc2b + 262144;                     // 51.4 MB

  cvt_weights_kernel<<<512, 256, 0, stream>>>(fc1, fc2, fc1b, fc2b);
  neocell_bn_kernel<<<dim3(14, 32, 2), 128, 0, stream>>>(
      x, wa1, wb1, wa2, wb2, bnw, bnb, bnm, bnv, y1);
  fused_mlp_kernel<<<dim3(2, 784), 256, 0, stream>>>(y1, fc1b, fc2b, x, out);
}